// Round 9
// baseline (74.801 us; speedup 1.0000x reference)
//
#include <hip/hip_runtime.h>

// Problem constants (fixed shapes from setup_inputs)
constexpr int NB = 8;     // batch
constexpr int ND = 1024;  // d = 32*32 cells
constexpr int NS = 500;   // noise samples n
constexpr int NK = 16;    // k
constexpr int NC = 3;     // channels
constexpr int NH = 1024;  // H
constexpr int NW = 1024;  // W
constexpr int NP = 64;    // patch size
constexpr int PTOP = 16;  // (p - sh)/2
constexpr int PLEFT = 16; // (p - sw)/2
constexpr float SIGMA = 0.05f;

// ---- Phase 1: normalize (blocks 0-7) + zero counts (all 64 blocks) ----
__global__ void normalize_kernel(const float* __restrict__ scores,
                                 float* __restrict__ s_norm,
                                 int* __restrict__ counts) {
    int blk = blockIdx.x;   // 64 blocks
    int t = threadIdx.x;

    // zero counts: 8*16*1024 ints = 32768 int4; 512 int4 per block
    int4 z4 = make_int4(0, 0, 0, 0);
    ((int4*)counts)[blk * 512 + t] = z4;
    ((int4*)counts)[blk * 512 + 256 + t] = z4;

    if (blk >= NB) return;
    int b = blk;
    float v[4];
#pragma unroll
    for (int q = 0; q < 4; q++) v[q] = scores[b * ND + t + 256 * q];
    float mn = fminf(fminf(v[0], v[1]), fminf(v[2], v[3]));
    float mx = fmaxf(fmaxf(v[0], v[1]), fmaxf(v[2], v[3]));
#pragma unroll
    for (int off = 1; off < 64; off <<= 1) {
        mn = fminf(mn, __shfl_xor(mn, off));
        mx = fmaxf(mx, __shfl_xor(mx, off));
    }
    __shared__ float smn[4], smx[4];
    int wave = t >> 6, lane = t & 63;
    if (lane == 0) { smn[wave] = mn; smx[wave] = mx; }
    __syncthreads();
    mn = fminf(fminf(smn[0], smn[1]), fminf(smn[2], smn[3]));
    mx = fmaxf(fmaxf(smx[0], smx[1]), fmaxf(smx[2], smx[3]));
    float den = mx - mn + 1e-5f;
#pragma unroll
    for (int q = 0; q < 4; q++)
        s_norm[b * ND + t + 256 * q] = (v[q] - mn) / den;
}

// ---------------- Phase 2: wave-per-sample top-16 -> integer histogram ----------------
__global__ void topk_kernel(const float* __restrict__ s_norm,
                            const float* __restrict__ noise,
                            int* __restrict__ counts) {
    int t = threadIdx.x;
    int wave = t >> 6, lane = t & 63;
    int sid = blockIdx.x * 4 + wave;          // 0 .. NB*NS-1 (grid is exact)
    int b = sid / NS;

    const float* sp = s_norm + b * ND;
    const float* npp = noise + (size_t)sid * ND;

    float v[16];
#pragma unroll
    for (int q = 0; q < 16; q++) {
        int j = q * 64 + lane;
        v[q] = sp[j] + npp[j] * SIGMA;
    }

    int myj = 0x7fffffff;
    for (int it = 0; it < NK; it++) {
        float bv = v[0];
        int bq = 0;
#pragma unroll
        for (int q = 1; q < 16; q++)
            if (v[q] > bv) { bv = v[q]; bq = q; }
        int bj = bq * 64 + lane;
#pragma unroll
        for (int off = 1; off < 64; off <<= 1) {
            float ov = __shfl_xor(bv, off);
            int oj = __shfl_xor(bj, off);
            if (ov > bv || (ov == bv && oj < bj)) { bv = ov; bj = oj; }
        }
        if (lane == it) myj = bj;
        int wq = bj >> 6, wl = bj & 63;
#pragma unroll
        for (int q = 0; q < 16; q++)
            v[q] = (q == wq && lane == wl) ? -1e30f : v[q];
    }

    int rank = 0;
#pragma unroll
    for (int u = 0; u < NK; u++) {
        int other = __shfl(myj, u);
        rank += (other < myj) ? 1 : 0;
    }
    if (lane < NK)
        atomicAdd(&counts[(b * NK + rank) * ND + myj], 1);
}

// ---------------- Phase 2.5: per-batch union of nonzero cells ----------------
// Block per b. Entry = packed (i<<15)|(j<<5)|edge_flags; + 16 f32 weights.
__global__ void union_kernel(const int* __restrict__ counts,
                             int* __restrict__ ucell,
                             float* __restrict__ uw,
                             int* __restrict__ nunion) {
    int b = blockIdx.x;
    int t = threadIdx.x;
    int lane = t & 63, wave = t >> 6;
    const int* cp = counts + b * NK * ND;

    unsigned nz = 0;
    for (int kk = 0; kk < NK; kk++) {
        int4 c4 = *(const int4*)(cp + kk * ND + t * 4);
        if (c4.x) nz |= 1;
        if (c4.y) nz |= 2;
        if (c4.z) nz |= 4;
        if (c4.w) nz |= 8;
    }
    int cnt = __popc(nz);
    int incl = cnt;
#pragma unroll
    for (int off = 1; off < 64; off <<= 1) {
        int o = __shfl_up(incl, off);
        if (lane >= off) incl += o;
    }
    int excl = incl - cnt;
    __shared__ int wtot[4];
    if (lane == 63) wtot[wave] = incl;
    __syncthreads();
    int base = 0;
    for (int w = 0; w < wave; w++) base += wtot[w];
    int pos = base + excl;

    const float invn = 1.0f / (float)NS;
    int* up = ucell + b * ND;
    float* wp = uw + (size_t)b * ND * NK;
#pragma unroll
    for (int q = 0; q < 4; q++) {
        if (nz & (1u << q)) {
            int cell = t * 4 + q;
            int i = cell >> 5, j = cell & 31;
            int ent = (i << 15) | (j << 5) |
                      ((i == 0) ? 1 : 0) | ((i == 31) ? 2 : 0) |
                      ((j == 0) ? 4 : 0) | ((j == 31) ? 8 : 0);
            up[pos] = ent;
            for (int kk = 0; kk < NK; kk++)
                wp[(size_t)pos * NK + kk] = (float)cp[kk * ND + cell] * invn;
            pos++;
        }
    }
    if (t == 0) nunion[b] = wtot[0] + wtot[1] + wtot[2] + wtot[3];
}

// ---------------- Phase 3: union gather, one wave per output row, 16 kk ----------------
// Grid: blk = y*24 + bc (bc = b*3+c; 24%8==0 so blk%8==bc%8 pins each image's
// 64 row-blocks to one XCD). One 64-lane wave per block: lane = column x.
// Entry words and weights are indexed by LOOP-UNIFORM e only -> compiler emits
// scalar s_load (SMEM pipe): no LDS, no barriers, no vector-load traffic for
// the tables. x-loads are the ONLY vector loads.
//
// CRITICAL FIX vs rounds 3-7: phase A issues 16 RAW loads (select applied to
// the ADDRESS, never to the loaded value) with zero consumers, so the compiler
// can keep 16 loads in flight (vmcnt batching). Phase B re-derives the ok
// predicate and applies select + FMA. sched_barrier(0) pins the A/B split.
// Previous rounds consumed v via cndmask in the same iteration -> one
// s_waitcnt vmcnt(0) per entry -> MLP=1 -> ~50 us. Predicted now: ~8-12 us.
__global__ void __launch_bounds__(64)
gather_kernel(const int* __restrict__ ucell,
              const float* __restrict__ uw,
              const int* __restrict__ nunion,
              const float* __restrict__ x_high,
              float* __restrict__ out) {
    int blk = blockIdx.x;
    int bc = blk % 24;
    int y  = blk / 24;           // 0..63
    int b = bc / 3, c = bc % 3;
    int x = threadIdx.x;         // 0..63 (one wave)

    int U = nunion[b];
    const int* up = ucell + b * ND;                    // uniform base
    const float* wp = uw + (size_t)b * ND * NK;        // uniform base
    const float* xp = x_high + (size_t)bc * (NH * NW);

    int ym = y - PTOP;           // [-16, 48), uniform per block
    int xm = x - PLEFT;          // [-16, 48), per lane
    int off = ym * NW + xm;
    int mask = ((ym < 0) ? 1 : 0) | ((ym >= 32) ? 2 : 0) |
               ((xm < 0) ? 4 : 0) | ((xm >= 32) ? 8 : 0);

    float acc[16];
#pragma unroll
    for (int q = 0; q < 16; q++) acc[q] = 0.f;

    for (int base = 0; base < U; base += 16) {
        float vv[16];
        // phase A: 16 independent RAW loads; guarded address, value untouched
#pragma unroll
        for (int j = 0; j < 16; j++) {
            int e = base + j;
            int ent = up[e < U ? e : 0];               // s_load, uniform
            bool ok = (e < U) && ((ent & mask) == 0);
            int idx = ok ? ((ent & ~15) + off) : 0;    // select on ADDRESS
            vv[j] = xp[idx];                           // no consumer here
        }
        __builtin_amdgcn_sched_barrier(0);             // keep A/B separated
        // phase B: consume; weights via uniform s_load, FMA w/ SGPR operand
#pragma unroll
        for (int j = 0; j < 16; j++) {
            int e = base + j;
            int es = e < U ? e : 0;
            int ent = up[es];                          // s_load (cached)
            bool ok = (e < U) && ((ent & mask) == 0);
            float v = ok ? vv[j] : 0.f;
            const float* wq = wp + (size_t)es * NK;
#pragma unroll
            for (int q = 0; q < 16; q++)
                acc[q] += wq[q] * v;                   // wq[q] -> s_load
        }
    }

#pragma unroll
    for (int q = 0; q < 16; q++)
        out[((size_t)(b * NK + q) * NC + c) * (NP * NP) + y * NP + x] = acc[q];
}

extern "C" void kernel_launch(void* const* d_in, const int* in_sizes, int n_in,
                              void* d_out, int out_size, void* d_ws, size_t ws_size,
                              hipStream_t stream) {
    const float* scores = (const float*)d_in[0];
    const float* x_high = (const float*)d_in[1];
    const float* noise  = (const float*)d_in[2];

    char* ws = (char*)d_ws;
    float* s_norm = (float*)ws;                            // 32 KB
    int* counts   = (int*)(ws + 32 * 1024);                // 512 KB (int4-aligned)
    int* ucell    = (int*)(ws + 544 * 1024);               // 32 KB
    float* uw     = (float*)(ws + 576 * 1024);             // 512 KB
    int* nunion   = (int*)(ws + 1088 * 1024);              // 32 B

    normalize_kernel<<<64, 256, 0, stream>>>(scores, s_norm, counts);
    topk_kernel<<<NB * NS / 4, 256, 0, stream>>>(s_norm, noise, counts);
    union_kernel<<<NB, 256, 0, stream>>>(counts, ucell, uw, nunion);
    gather_kernel<<<24 * 64, 64, 0, stream>>>(ucell, uw, nunion, x_high,
                                              (float*)d_out);
}

// Round 10
// 62.777 us; speedup vs baseline: 1.1915x; 1.1915x over previous
//
#include <hip/hip_runtime.h>

// Problem constants (fixed shapes from setup_inputs)
constexpr int NB = 8;     // batch
constexpr int ND = 1024;  // d = 32*32 cells
constexpr int NS = 500;   // noise samples n
constexpr int NK = 16;    // k
constexpr int NC = 3;     // channels
constexpr int NH = 1024;  // H
constexpr int NW = 1024;  // W
constexpr int NP = 64;    // patch size
constexpr int PTOP = 16;  // (p - sh)/2
constexpr int PLEFT = 16; // (p - sw)/2
constexpr float SIGMA = 0.05f;

// ---- Phase 1: normalize (blocks 0-7) + zero counts (all 64 blocks) ----
__global__ void normalize_kernel(const float* __restrict__ scores,
                                 float* __restrict__ s_norm,
                                 int* __restrict__ counts) {
    int blk = blockIdx.x;   // 64 blocks
    int t = threadIdx.x;

    // zero counts: 8*16*1024 ints = 32768 int4; 512 int4 per block
    int4 z4 = make_int4(0, 0, 0, 0);
    ((int4*)counts)[blk * 512 + t] = z4;
    ((int4*)counts)[blk * 512 + 256 + t] = z4;

    if (blk >= NB) return;
    int b = blk;
    float v[4];
#pragma unroll
    for (int q = 0; q < 4; q++) v[q] = scores[b * ND + t + 256 * q];
    float mn = fminf(fminf(v[0], v[1]), fminf(v[2], v[3]));
    float mx = fmaxf(fmaxf(v[0], v[1]), fmaxf(v[2], v[3]));
#pragma unroll
    for (int off = 1; off < 64; off <<= 1) {
        mn = fminf(mn, __shfl_xor(mn, off));
        mx = fmaxf(mx, __shfl_xor(mx, off));
    }
    __shared__ float smn[4], smx[4];
    int wave = t >> 6, lane = t & 63;
    if (lane == 0) { smn[wave] = mn; smx[wave] = mx; }
    __syncthreads();
    mn = fminf(fminf(smn[0], smn[1]), fminf(smn[2], smn[3]));
    mx = fmaxf(fmaxf(smx[0], smx[1]), fmaxf(smx[2], smx[3]));
    float den = mx - mn + 1e-5f;
#pragma unroll
    for (int q = 0; q < 4; q++)
        s_norm[b * ND + t + 256 * q] = (v[q] - mn) / den;
}

// ---------------- Phase 2: wave-per-sample top-16 -> integer histogram ----------------
__global__ void topk_kernel(const float* __restrict__ s_norm,
                            const float* __restrict__ noise,
                            int* __restrict__ counts) {
    int t = threadIdx.x;
    int wave = t >> 6, lane = t & 63;
    int sid = blockIdx.x * 4 + wave;          // 0 .. NB*NS-1 (grid is exact)
    int b = sid / NS;

    const float* sp = s_norm + b * ND;
    const float* npp = noise + (size_t)sid * ND;

    float v[16];
#pragma unroll
    for (int q = 0; q < 16; q++) {
        int j = q * 64 + lane;
        v[q] = sp[j] + npp[j] * SIGMA;
    }

    int myj = 0x7fffffff;
    for (int it = 0; it < NK; it++) {
        float bv = v[0];
        int bq = 0;
#pragma unroll
        for (int q = 1; q < 16; q++)
            if (v[q] > bv) { bv = v[q]; bq = q; }
        int bj = bq * 64 + lane;
#pragma unroll
        for (int off = 1; off < 64; off <<= 1) {
            float ov = __shfl_xor(bv, off);
            int oj = __shfl_xor(bj, off);
            if (ov > bv || (ov == bv && oj < bj)) { bv = ov; bj = oj; }
        }
        if (lane == it) myj = bj;
        int wq = bj >> 6, wl = bj & 63;
#pragma unroll
        for (int q = 0; q < 16; q++)
            v[q] = (q == wq && lane == wl) ? -1e30f : v[q];
    }

    int rank = 0;
#pragma unroll
    for (int u = 0; u < NK; u++) {
        int other = __shfl(myj, u);
        rank += (other < myj) ? 1 : 0;
    }
    if (lane < NK)
        atomicAdd(&counts[(b * NK + rank) * ND + myj], 1);
}

// ---------------- Phase 2.5: per-batch union of nonzero cells ----------------
// Block per b. Entry = packed (i<<15)|(j<<5)|edge_flags; + 16 f32 weights.
__global__ void union_kernel(const int* __restrict__ counts,
                             int* __restrict__ ucell,
                             float* __restrict__ uw,
                             int* __restrict__ nunion) {
    int b = blockIdx.x;
    int t = threadIdx.x;
    int lane = t & 63, wave = t >> 6;
    const int* cp = counts + b * NK * ND;

    unsigned nz = 0;
    for (int kk = 0; kk < NK; kk++) {
        int4 c4 = *(const int4*)(cp + kk * ND + t * 4);
        if (c4.x) nz |= 1;
        if (c4.y) nz |= 2;
        if (c4.z) nz |= 4;
        if (c4.w) nz |= 8;
    }
    int cnt = __popc(nz);
    int incl = cnt;
#pragma unroll
    for (int off = 1; off < 64; off <<= 1) {
        int o = __shfl_up(incl, off);
        if (lane >= off) incl += o;
    }
    int excl = incl - cnt;
    __shared__ int wtot[4];
    if (lane == 63) wtot[wave] = incl;
    __syncthreads();
    int base = 0;
    for (int w = 0; w < wave; w++) base += wtot[w];
    int pos = base + excl;

    const float invn = 1.0f / (float)NS;
    int* up = ucell + b * ND;
    float* wp = uw + (size_t)b * ND * NK;
#pragma unroll
    for (int q = 0; q < 4; q++) {
        if (nz & (1u << q)) {
            int cell = t * 4 + q;
            int i = cell >> 5, j = cell & 31;
            int ent = (i << 15) | (j << 5) |
                      ((i == 0) ? 1 : 0) | ((i == 31) ? 2 : 0) |
                      ((j == 0) ? 4 : 0) | ((j == 31) ? 8 : 0);
            up[pos] = ent;
            for (int kk = 0; kk < NK; kk++)
                wp[(size_t)pos * NK + kk] = (float)cp[kk * ND + cell] * invn;
            pos++;
        }
    }
    if (t == 0) nunion[b] = wtot[0] + wtot[1] + wtot[2] + wtot[3];
}

// ---------------- Phase 3: union gather ----------------
// Grid: blk = g*24 + bc (bc = b*3+c; 24%8==0 -> all of one image's blocks on
// one XCD). Block = 4-row group g (y = 4g+dy, dy=t>>6; x = t&63). 1 px/thread,
// all 16 kk in registers -> each loaded pixel feeds 16 FMAs; every output
// written exactly once (no atomics).
// Cost model fixes vs R5-R8 (all measured):
//  - weights staged ONCE in LDS (48 KB), read via broadcast ds_read_b128
//    -> kills R7/R8's scalar-K$ thrash (weights 19KB/batch > K$).
//  - 8-deep double-buffered chunks: loads issued RAW (select on ADDRESS,
//    ok-bits saved), value-select + FMA happen one chunk later -> >=8 loads
//    in flight per wave while 128 FMAs of the previous chunk run.
constexpr int MAXE = 768;

#define LOADCH(V, E, OKB, BASE)                                           \
    {                                                                     \
        OKB = 0;                                                          \
        _Pragma("unroll")                                                 \
        for (int j = 0; j < 8; j++) {                                     \
            int e = (BASE) + j;                                           \
            int es = (e < mc) ? e : 0;                                    \
            E[j] = es;                                                    \
            int ent = lc[es];                                             \
            bool ok = (e < mc) && ((ent & mask) == 0);                    \
            OKB |= (ok ? 1 : 0) << j;                                     \
            int idx = ok ? ((ent & ~15) + off) : 0;                       \
            V[j] = xp[idx];                                               \
        }                                                                 \
    }

#define CONSCH(V, E, OKB)                                                 \
    {                                                                     \
        _Pragma("unroll")                                                 \
        for (int j = 0; j < 8; j++) {                                     \
            int es = E[j];                                                \
            float v = ((OKB >> j) & 1) ? V[j] : 0.f;                      \
            float4 w0 = lw4[es * 4 + 0];                                  \
            float4 w1 = lw4[es * 4 + 1];                                  \
            float4 w2 = lw4[es * 4 + 2];                                  \
            float4 w3 = lw4[es * 4 + 3];                                  \
            acc[0]  += w0.x * v; acc[1]  += w0.y * v;                     \
            acc[2]  += w0.z * v; acc[3]  += w0.w * v;                     \
            acc[4]  += w1.x * v; acc[5]  += w1.y * v;                     \
            acc[6]  += w1.z * v; acc[7]  += w1.w * v;                     \
            acc[8]  += w2.x * v; acc[9]  += w2.y * v;                     \
            acc[10] += w2.z * v; acc[11] += w2.w * v;                     \
            acc[12] += w3.x * v; acc[13] += w3.y * v;                     \
            acc[14] += w3.z * v; acc[15] += w3.w * v;                     \
        }                                                                 \
    }

__global__ void __launch_bounds__(256)
gather_kernel(const int* __restrict__ ucell,
              const float* __restrict__ uw,
              const int* __restrict__ nunion,
              const float* __restrict__ x_high,
              float* __restrict__ out) {
    int blk = blockIdx.x;
    int bc = blk % 24;
    int g  = blk / 24;           // 0..15
    int b = bc / 3, c = bc % 3;
    int t = threadIdx.x;
    int x = t & 63;
    int dy = t >> 6;             // 0..3 (wave id)
    int y = g * 4 + dy;

    int U = nunion[b];
    int mc = U < MAXE ? U : MAXE;

    __shared__ int lc[MAXE];           // 3 KB
    __shared__ float4 lw4[MAXE * 4];   // 48 KB

    for (int i = t; i < mc; i += 256) {
        lc[i] = ucell[b * ND + i];
        const float4* ws = (const float4*)(uw + (size_t)(b * ND + i) * NK);
        lw4[i * 4 + 0] = ws[0];
        lw4[i * 4 + 1] = ws[1];
        lw4[i * 4 + 2] = ws[2];
        lw4[i * 4 + 3] = ws[3];
    }
    __syncthreads();

    const float* xp = x_high + (size_t)bc * (NH * NW);
    int ym = y - PTOP;           // [-16, 48), wave-uniform
    int xm = x - PLEFT;          // [-16, 48), per lane
    int off = ym * NW + xm;
    int mask = ((ym < 0) ? 1 : 0) | ((ym >= 32) ? 2 : 0) |
               ((xm < 0) ? 4 : 0) | ((xm >= 32) ? 8 : 0);

    float acc[16];
#pragma unroll
    for (int q = 0; q < 16; q++) acc[q] = 0.f;

    // double-buffered 8-deep chunk pipeline (named buffers: static indexing)
    float va[8], vb[8];
    int ea[8], eb[8];
    int oka, okb;

    int nch = (mc + 7) >> 3;
    LOADCH(va, ea, oka, 0);
    for (int ci = 0; ci < nch; ci += 2) {
        LOADCH(vb, eb, okb, (ci + 1) * 8);
        CONSCH(va, ea, oka);
        LOADCH(va, ea, oka, (ci + 2) * 8);   // beyond-mc chunks: ok=0, harmless
        CONSCH(vb, eb, okb);
    }

    // overflow tail (U > MAXE) — correctness only, statistically never runs
    for (int e = MAXE; e < U; e++) {
        int ent = ucell[b * ND + e];
        bool ok = ((ent & mask) == 0);
        int idx = ok ? ((ent & ~15) + off) : 0;
        float v = xp[idx];
        v = ok ? v : 0.f;
        const float* wq = uw + (size_t)(b * ND + e) * NK;
#pragma unroll
        for (int q = 0; q < 16; q++) acc[q] += wq[q] * v;
    }

#pragma unroll
    for (int q = 0; q < 16; q++)
        out[((size_t)(b * NK + q) * NC + c) * (NP * NP) + y * NP + x] = acc[q];
}

extern "C" void kernel_launch(void* const* d_in, const int* in_sizes, int n_in,
                              void* d_out, int out_size, void* d_ws, size_t ws_size,
                              hipStream_t stream) {
    const float* scores = (const float*)d_in[0];
    const float* x_high = (const float*)d_in[1];
    const float* noise  = (const float*)d_in[2];

    char* ws = (char*)d_ws;
    float* s_norm = (float*)ws;                            // 32 KB
    int* counts   = (int*)(ws + 32 * 1024);                // 512 KB (int4-aligned)
    int* ucell    = (int*)(ws + 544 * 1024);               // 32 KB
    float* uw     = (float*)(ws + 576 * 1024);             // 512 KB
    int* nunion   = (int*)(ws + 1088 * 1024);              // 32 B

    normalize_kernel<<<64, 256, 0, stream>>>(scores, s_norm, counts);
    topk_kernel<<<NB * NS / 4, 256, 0, stream>>>(s_norm, noise, counts);
    union_kernel<<<NB, 256, 0, stream>>>(counts, ucell, uw, nunion);
    gather_kernel<<<24 * 16, 256, 0, stream>>>(ucell, uw, nunion, x_high,
                                               (float*)d_out);
}